// Round 14
// baseline (105.977 us; speedup 1.0000x reference)
//
#include <hip/hip_runtime.h>
#include <hip/hip_bf16.h>

// InfoNCE fused: loss = (1/N) sum_i [ log(sum_j exp(sim_ij)) - sim_ii ]
// sim = (z1/||z1||)@(z2/||z2||)^T / tau.  lse over the FULL row.
//
// z1f = bf16(z1n * log2(e)/tau) so exp(sim) = exp2(MFMA output).
// exp2 via Schraudolph bit-trick (R8: proved trans unit was NOT the wall).
//
// R21 vs R13 (FAILED, absmax 12.69 = loss magnitude): the R13 edit dropped
// the per-launch cnt[]=0 init from the norm kernel while the ticket still
// tests v==CS-1 -> counter never reset across harness replays -> finalize
// never ran on the graded launch -> out stayed 0. NOT a TLP failure; the
// experiment never executed. Fix: restore R12's cnt zeroing (stream-ordered
// before main each launch). TLP config unchanged from R13:
// NW 4->8, NSETS 4->2, BM/grid/LDS/B-traffic identical, (512,8).
// Predict (same as R13): main ~28-34us if TLP-starved, occ 70-95%,
// MfmaUtil ~45%, dur ~85-90, absmax 0. If main unchanged at high occ ->
// dependency-fundamental wall -> declare practical ceiling.

typedef __bf16  bf16x8 __attribute__((ext_vector_type(8)));
typedef __bf16  bf16x4 __attribute__((ext_vector_type(4)));
typedef float   f32x4  __attribute__((ext_vector_type(4)));

#if __has_builtin(__builtin_amdgcn_logf)
#define LOG2F(x) __builtin_amdgcn_logf(x)    // raw v_log_f32
#else
#define LOG2F(x) log2f(x)
#endif

// Schraudolph fast exp2: 2^x ~= bitcast_f32((int)(x*2^23 + C)).
// C tuned mean-zero over uniform frac: (127<<23) - 0.05756*2^23.
// x in [-29.2, 29.2] -> no over/underflow. 3 full-rate VALU ops.
__device__ __forceinline__ float exp2_schraudolph(float x) {
    float y = fmaf(x, 8388608.0f, 1064870379.0f);
    return __int_as_float((int)y);
}

#define DDIM   64
#define TILEB  2048         // bytes per fragment-ordered 16-col tile
#define NSETS  2            // 16-row MFMA sets per wave (32 rows/wave)
#define NW     8            // waves per block (512 threads)
#define BM     (NW * NSETS * 16)   // 256 rows per block (unchanged)
#define CS     64           // column splits -> grid (64,64) = 4096 blocks
#define LDSB   32768        // colspan(256) * 128 B  (N == 16384)

#define GLOAD_LDS(g, l)                                                      \
    __builtin_amdgcn_global_load_lds(                                        \
        (const __attribute__((address_space(1))) void*)(g),                  \
        (__attribute__((address_space(3))) void*)(l), 16, 0, 0)

// ---------------------------------------------------------------- normalize
// One block per 16-row tile. Thread (r = tid>>4, c = tid&15) loads
// z[row, 4c..4c+4), reduces ||row|| over its 16-lane group, writes the 4
// bf16 values into fragment order:
//   byte off(tile) = (c>>3)*1024 + ((c>>1)&3)*256 + r*16 + (c&1)*8
// Same thread holds row i of both views -> posv[i] = dot(z1f_i, z2f_i).
// Zeroes rowsum, the per-row-block completion counters, and d_out --
// ALL re-zeroed every launch, stream-ordered before the main kernel.
__global__ __launch_bounds__(256) void norm_frag_kernel(
    const float* __restrict__ z1, const float* __restrict__ z2,
    __hip_bfloat16* __restrict__ z1f, __hip_bfloat16* __restrict__ z2f,
    float* __restrict__ rowsum, float* __restrict__ posv,
    int* __restrict__ cnt, float* __restrict__ out, float scale1, int N)
{
    const int tid  = threadIdx.x;
    const int r    = tid >> 4, c = tid & 15;
    const int tile = blockIdx.x;
    const size_t row = (size_t)tile * 16 + r;
    const size_t off = (size_t)tile * TILEB
                     + ((c >> 3) << 10) + (((c >> 1) & 3) << 8)
                     + (r << 4) + ((c & 1) << 3);

    bf16x4 o1, o2;
    {
        float4 v = *(const float4*)(z1 + row * DDIM + c * 4);
        float ss = v.x*v.x + v.y*v.y + v.z*v.z + v.w*v.w;
        #pragma unroll
        for (int o = 8; o; o >>= 1) ss += __shfl_xor(ss, o);
        float inv = scale1 / fmaxf(sqrtf(ss), 1e-12f);
        o1 = (bf16x4){ __float2bfloat16(v.x*inv), __float2bfloat16(v.y*inv),
                       __float2bfloat16(v.z*inv), __float2bfloat16(v.w*inv) };
        *(bf16x4*)((char*)z1f + off) = o1;
    }
    {
        float4 v = *(const float4*)(z2 + row * DDIM + c * 4);
        float ss = v.x*v.x + v.y*v.y + v.z*v.z + v.w*v.w;
        #pragma unroll
        for (int o = 8; o; o >>= 1) ss += __shfl_xor(ss, o);
        float inv = 1.0f / fmaxf(sqrtf(ss), 1e-12f);
        o2 = (bf16x4){ __float2bfloat16(v.x*inv), __float2bfloat16(v.y*inv),
                       __float2bfloat16(v.z*inv), __float2bfloat16(v.w*inv) };
        *(bf16x4*)((char*)z2f + off) = o2;
    }

    // posv[row] = dot of the bf16-rounded rows (log2-domain positive logit)
    float p = (float)o1[0]*(float)o2[0] + (float)o1[1]*(float)o2[1]
            + (float)o1[2]*(float)o2[2] + (float)o1[3]*(float)o2[3];
    #pragma unroll
    for (int o = 8; o; o >>= 1) p += __shfl_xor(p, o);
    if (c == 0) posv[row] = p;

    if (tid < 16) rowsum[(size_t)tile * 16 + tid] = 0.f;
    if (tile == 0) {
        if (tid < CS) cnt[tid] = 0;   // one counter per row-block (NBX==CS==64)
        if (tid == 0) *out = 0.f;
    }
}

// ---------------------------------------------------------------- main
// Per block: 256 rows (8 waves x 2 sets) x colspan=256 cols. Whole 32KB B
// panel staged to LDS up front (shared by all 8 waves), one barrier, 16
// barrier-free iterations. Then rowsum atomics, vmcnt(0), completion
// ticket; last of the 64 contributor blocks finalizes its 256 rows
// inline via coherent L2 RMW reads.
__global__ __launch_bounds__(512, 8) void infonce_main_kernel(
    const __hip_bfloat16* __restrict__ z1f,
    const __hip_bfloat16* __restrict__ z2f,
    float* __restrict__ rowsum, const float* __restrict__ posv,
    int* __restrict__ cnt, float* __restrict__ out, int N)
{
    __shared__ __align__(16) char ldsb[LDSB];   // 32 KB

    const int tid  = threadIdx.x;
    const int wave = tid >> 6;
    const int lane = tid & 63;
    const int q    = lane >> 4;
    const int l15  = lane & 15;

    const int colspan = N / CS;          // 256
    const int ntiles  = colspan >> 4;    // 16
    const int c0      = blockIdx.y * colspan;
    const int vx      = blockIdx.x;
    const int wr      = vx * BM + wave * (NSETS * 16);

    const char* gB = (const char*)z2f + (size_t)(c0 >> 4) * TILEB;

    // stage the whole B panel: 32 chunks of 1KB, wave-interleaved (4/wave)
    #pragma unroll
    for (int i = 0; i < 32 / NW; ++i) {
        const int c = i * NW + wave;
        GLOAD_LDS(gB + (c << 10) + lane * 16, ldsb + (c << 10));
    }

    // A fragments (fragment-ordered global, coalesced)
    bf16x8 a0[NSETS], a1[NSETS];
    #pragma unroll
    for (int s = 0; s < NSETS; ++s) {
        const char* ab = (const char*)z1f + (size_t)((wr >> 4) + s) * TILEB + lane * 16;
        a0[s] = *(const bf16x8*)(ab);
        a1[s] = *(const bf16x8*)(ab + 1024);
    }

    float sum[NSETS * 4];
    #pragma unroll
    for (int k = 0; k < NSETS * 4; ++k) sum[k] = 0.f;

    asm volatile("s_waitcnt vmcnt(0)" ::: "memory");
    __syncthreads();                      // LDS panel ready

    const char* bb = ldsb + lane * 16;
    const f32x4 kzero = {0.f, 0.f, 0.f, 0.f};

    #pragma unroll 4
    for (int t = 0; t < ntiles; ++t) {
        bf16x8 b0 = *(const bf16x8*)(bb + t * TILEB);
        bf16x8 b1 = *(const bf16x8*)(bb + t * TILEB + 1024);
        #pragma unroll
        for (int s = 0; s < NSETS; ++s) {
            f32x4 acc = __builtin_amdgcn_mfma_f32_16x16x32_bf16(a0[s], b0, kzero, 0, 0, 0);
            acc = __builtin_amdgcn_mfma_f32_16x16x32_bf16(a1[s], b1, acc, 0, 0, 0);
            sum[s * 4 + 0] += exp2_schraudolph(acc[0]);
            sum[s * 4 + 1] += exp2_schraudolph(acc[1]);
            sum[s * 4 + 2] += exp2_schraudolph(acc[2]);
            sum[s * 4 + 3] += exp2_schraudolph(acc[3]);
        }
    }

    // reduce each row-sum across the 16 lanes of the quad, then atomics
    #pragma unroll
    for (int k = 0; k < NSETS * 4; ++k) {
        float v = sum[k];
        #pragma unroll
        for (int o = 1; o < 16; o <<= 1) v += __shfl_xor(v, o);
        sum[k] = v;
    }
    if (l15 == 0) {
        #pragma unroll
        for (int s = 0; s < NSETS; ++s)
            #pragma unroll
            for (int i = 0; i < 4; ++i)
                atomicAdd(&rowsum[wr + s * 16 + q * 4 + i], sum[s * 4 + i]);
    }

    // ---- completion ticket (NO fence: atomics complete at coherent point)
    asm volatile("s_waitcnt vmcnt(0)" ::: "memory");  // my atomics retired
    __syncthreads();              // all waves retired; ldsb reads all done
    if (tid == 0) {
        int v = atomicAdd(&cnt[vx], 1);
        *(int*)ldsb = (v == CS - 1);      // reuse dead LDS for the flag
    }
    __syncthreads();

    if (*(const int*)ldsb && tid < BM) {
        // all 64 contributor blocks done; read coherently via L2 RMW
        const int row = vx * BM + tid;    // first 256 threads == 256 rows
        float rs  = atomicAdd(&rowsum[row], 0.0f);
        float acc = (LOG2F(rs) - posv[row]) * (0.69314718055994531f / (float)N);
        #pragma unroll
        for (int o = 32; o; o >>= 1) acc += __shfl_xor(acc, o);
        if ((tid & 63) == 0) atomicAdd(out, acc);
    }
}

// ---------------------------------------------------------------- launch
extern "C" void kernel_launch(void* const* d_in, const int* in_sizes, int n_in,
                              void* d_out, int out_size, void* d_ws, size_t ws_size,
                              hipStream_t stream)
{
    const float* z1 = (const float*)d_in[0];
    const float* z2 = (const float*)d_in[1];
    const int N = in_sizes[0] / DDIM;   // 16384

    char* ws = (char*)d_ws;
    __hip_bfloat16* z1f = (__hip_bfloat16*)ws;                  // N*128 B (2 MB)
    __hip_bfloat16* z2f = z1f + (size_t)N * DDIM;               // N*128 B (2 MB)
    float* rowsum = (float*)(ws + 2 * (size_t)N * DDIM * 2);    // N*4 B
    float* posv   = rowsum + N;                                 // N*4 B
    int*   cnt    = (int*)(posv + N);                           // 64*4 B

    const float kScale = 28.853900817779268f;   // log2(e) / 0.05

    norm_frag_kernel<<<N / 16, 256, 0, stream>>>(z1, z2, z1f, z2f, rowsum,
                                                 posv, cnt, (float*)d_out,
                                                 kScale, N);

    dim3 grid(N / BM, CS);
    infonce_main_kernel<<<grid, NW * 64, 0, stream>>>(z1f, z2f, rowsum, posv,
                                                      cnt, (float*)d_out, N);
}

// Round 16
// 104.037 us; speedup vs baseline: 1.0186x; 1.0186x over previous
//
#include <hip/hip_runtime.h>
#include <hip/hip_bf16.h>

// InfoNCE fused: loss = (1/N) sum_i [ log(sum_j exp(sim_ij)) - sim_ii ]
// sim = (z1/||z1||)@(z2/||z2||)^T / tau.  lse over the FULL row.
//
// z1f = bf16(z1n * log2(e)/tau) so exp(sim) = exp2(MFMA output).
// exp2 via Schraudolph bit-trick (R8: proved trans unit was NOT the wall).
//
// R23: resubmit of R22 (= R12-verified config, dur 103.9, main 48.6) --
// R22's bench hit the "container failed twice" infra signature on a
// known-good kernel, same as R0 (which failed on the verified 106.4us
// kernel that then passed in R1). Kernel-independent infra failure rate
// is now 3-4/16 rounds; no edits on infra failures.
//
// Experiment matrix (all null on the 47+-2us main wall): occupancy
// 31->69% (R2/R14, VALUBusy pinned ~51% -> issue-port cap), explicit ILP
// ping-pong (R5), trans->VALU Schraudolph exp (R8), B-path L2-stream/
// phased-LDS/whole-panel (R2-R4), barrier-free loop (R4). Launch fusion
// 3->2 kernels saved only 2.5us (R12) -> ~50us non-kernel residual is
// fixed harness cost. If this run reproduces (~48us main, MfmaUtil ~28,
// VALUBusy ~47, occ ~34, absmax 0), practical ceiling is established.

typedef __bf16  bf16x8 __attribute__((ext_vector_type(8)));
typedef __bf16  bf16x4 __attribute__((ext_vector_type(4)));
typedef float   f32x4  __attribute__((ext_vector_type(4)));

#if __has_builtin(__builtin_amdgcn_logf)
#define LOG2F(x) __builtin_amdgcn_logf(x)    // raw v_log_f32
#else
#define LOG2F(x) log2f(x)
#endif

// Schraudolph fast exp2: 2^x ~= bitcast_f32((int)(x*2^23 + C)).
// C tuned mean-zero over uniform frac: (127<<23) - 0.05756*2^23.
// x in [-29.2, 29.2] -> no over/underflow. 3 full-rate VALU ops.
__device__ __forceinline__ float exp2_schraudolph(float x) {
    float y = fmaf(x, 8388608.0f, 1064870379.0f);
    return __int_as_float((int)y);
}

#define DDIM   64
#define TILEB  2048         // bytes per fragment-ordered 16-col tile
#define NSETS  4            // 16-row MFMA sets per wave (64 rows/wave)
#define NW     4            // waves per block
#define BM     (NW * NSETS * 16)   // 256 rows per block
#define CS     64           // column splits -> grid (64,64) = 4096 blocks
#define LDSB   32768        // colspan(256) * 128 B  (N == 16384)

#define GLOAD_LDS(g, l)                                                      \
    __builtin_amdgcn_global_load_lds(                                        \
        (const __attribute__((address_space(1))) void*)(g),                  \
        (__attribute__((address_space(3))) void*)(l), 16, 0, 0)

// ---------------------------------------------------------------- normalize
// One block per 16-row tile. Thread (r = tid>>4, c = tid&15) loads
// z[row, 4c..4c+4), reduces ||row|| over its 16-lane group, writes the 4
// bf16 values into fragment order:
//   byte off(tile) = (c>>3)*1024 + ((c>>1)&3)*256 + r*16 + (c&1)*8
// Same thread holds row i of both views -> posv[i] = dot(z1f_i, z2f_i).
// Zeroes rowsum, the per-row-block completion counters, and d_out --
// ALL re-zeroed every launch, stream-ordered before the main kernel.
__global__ __launch_bounds__(256) void norm_frag_kernel(
    const float* __restrict__ z1, const float* __restrict__ z2,
    __hip_bfloat16* __restrict__ z1f, __hip_bfloat16* __restrict__ z2f,
    float* __restrict__ rowsum, float* __restrict__ posv,
    int* __restrict__ cnt, float* __restrict__ out, float scale1, int N)
{
    const int tid  = threadIdx.x;
    const int r    = tid >> 4, c = tid & 15;
    const int tile = blockIdx.x;
    const size_t row = (size_t)tile * 16 + r;
    const size_t off = (size_t)tile * TILEB
                     + ((c >> 3) << 10) + (((c >> 1) & 3) << 8)
                     + (r << 4) + ((c & 1) << 3);

    bf16x4 o1, o2;
    {
        float4 v = *(const float4*)(z1 + row * DDIM + c * 4);
        float ss = v.x*v.x + v.y*v.y + v.z*v.z + v.w*v.w;
        #pragma unroll
        for (int o = 8; o; o >>= 1) ss += __shfl_xor(ss, o);
        float inv = scale1 / fmaxf(sqrtf(ss), 1e-12f);
        o1 = (bf16x4){ __float2bfloat16(v.x*inv), __float2bfloat16(v.y*inv),
                       __float2bfloat16(v.z*inv), __float2bfloat16(v.w*inv) };
        *(bf16x4*)((char*)z1f + off) = o1;
    }
    {
        float4 v = *(const float4*)(z2 + row * DDIM + c * 4);
        float ss = v.x*v.x + v.y*v.y + v.z*v.z + v.w*v.w;
        #pragma unroll
        for (int o = 8; o; o >>= 1) ss += __shfl_xor(ss, o);
        float inv = 1.0f / fmaxf(sqrtf(ss), 1e-12f);
        o2 = (bf16x4){ __float2bfloat16(v.x*inv), __float2bfloat16(v.y*inv),
                       __float2bfloat16(v.z*inv), __float2bfloat16(v.w*inv) };
        *(bf16x4*)((char*)z2f + off) = o2;
    }

    // posv[row] = dot of the bf16-rounded rows (log2-domain positive logit)
    float p = (float)o1[0]*(float)o2[0] + (float)o1[1]*(float)o2[1]
            + (float)o1[2]*(float)o2[2] + (float)o1[3]*(float)o2[3];
    #pragma unroll
    for (int o = 8; o; o >>= 1) p += __shfl_xor(p, o);
    if (c == 0) posv[row] = p;

    if (tid < 16) rowsum[(size_t)tile * 16 + tid] = 0.f;
    if (tile == 0) {
        if (tid < CS) cnt[tid] = 0;   // one counter per row-block (NBX==CS==64)
        if (tid == 0) *out = 0.f;
    }
}

// ---------------------------------------------------------------- main
// Per block: 256 rows (4 waves x 4 sets) x colspan=256 cols. Whole 32KB B
// panel staged to LDS up front, one barrier, 16 barrier-free iterations.
// Then rowsum atomics, vmcnt(0) (atomics complete at the device-coherent
// point -- NO threadfence, no L2 flush), completion ticket; the LAST of
// the 64 contributor blocks finalizes its 256 rows inline, reading rowsum
// coherently via atomicAdd(p, 0.0f) L2 RMW.
__global__ __launch_bounds__(256, 5) void infonce_main_kernel(
    const __hip_bfloat16* __restrict__ z1f,
    const __hip_bfloat16* __restrict__ z2f,
    float* __restrict__ rowsum, const float* __restrict__ posv,
    int* __restrict__ cnt, float* __restrict__ out, int N)
{
    __shared__ __align__(16) char ldsb[LDSB];   // 32 KB exactly -> 5 blocks/CU

    const int tid  = threadIdx.x;
    const int wave = tid >> 6;
    const int lane = tid & 63;
    const int q    = lane >> 4;
    const int l15  = lane & 15;

    const int colspan = N / CS;          // 256
    const int ntiles  = colspan >> 4;    // 16
    const int c0      = blockIdx.y * colspan;
    const int vx      = blockIdx.x;
    const int wr      = vx * BM + wave * (NSETS * 16);

    const char* gB = (const char*)z2f + (size_t)(c0 >> 4) * TILEB;

    // stage the whole B panel: 32 chunks of 1KB, wave-interleaved
    for (int i = 0; i < 32 / NW; ++i) {
        const int c = i * NW + wave;
        GLOAD_LDS(gB + (c << 10) + lane * 16, ldsb + (c << 10));
    }

    // A fragments (fragment-ordered global, coalesced)
    bf16x8 a0[NSETS], a1[NSETS];
    #pragma unroll
    for (int s = 0; s < NSETS; ++s) {
        const char* ab = (const char*)z1f + (size_t)((wr >> 4) + s) * TILEB + lane * 16;
        a0[s] = *(const bf16x8*)(ab);
        a1[s] = *(const bf16x8*)(ab + 1024);
    }

    float sum[NSETS * 4];
    #pragma unroll
    for (int k = 0; k < NSETS * 4; ++k) sum[k] = 0.f;

    asm volatile("s_waitcnt vmcnt(0)" ::: "memory");
    __syncthreads();                      // LDS panel ready

    const char* bb = ldsb + lane * 16;
    const f32x4 kzero = {0.f, 0.f, 0.f, 0.f};

    #pragma unroll 4
    for (int t = 0; t < ntiles; ++t) {
        bf16x8 b0 = *(const bf16x8*)(bb + t * TILEB);
        bf16x8 b1 = *(const bf16x8*)(bb + t * TILEB + 1024);
        #pragma unroll
        for (int s = 0; s < NSETS; ++s) {
            f32x4 acc = __builtin_amdgcn_mfma_f32_16x16x32_bf16(a0[s], b0, kzero, 0, 0, 0);
            acc = __builtin_amdgcn_mfma_f32_16x16x32_bf16(a1[s], b1, acc, 0, 0, 0);
            sum[s * 4 + 0] += exp2_schraudolph(acc[0]);
            sum[s * 4 + 1] += exp2_schraudolph(acc[1]);
            sum[s * 4 + 2] += exp2_schraudolph(acc[2]);
            sum[s * 4 + 3] += exp2_schraudolph(acc[3]);
        }
    }

    // reduce each row-sum across the 16 lanes of the quad, then atomics
    #pragma unroll
    for (int k = 0; k < NSETS * 4; ++k) {
        float v = sum[k];
        #pragma unroll
        for (int o = 1; o < 16; o <<= 1) v += __shfl_xor(v, o);
        sum[k] = v;
    }
    if (l15 == 0) {
        #pragma unroll
        for (int s = 0; s < NSETS; ++s)
            #pragma unroll
            for (int i = 0; i < 4; ++i)
                atomicAdd(&rowsum[wr + s * 16 + q * 4 + i], sum[s * 4 + i]);
    }

    // ---- completion ticket (NO fence: atomics complete at coherent point)
    asm volatile("s_waitcnt vmcnt(0)" ::: "memory");  // my atomics retired
    __syncthreads();              // all waves retired; ldsb reads all done
    if (tid == 0) {
        int v = atomicAdd(&cnt[vx], 1);
        *(int*)ldsb = (v == CS - 1);      // reuse dead LDS for the flag
    }
    __syncthreads();

    if (*(const int*)ldsb) {
        // all 64 contributor blocks done; read coherently via L2 RMW
        const int row = vx * BM + tid;    // 256 threads == 256 rows
        float rs  = atomicAdd(&rowsum[row], 0.0f);
        float acc = (LOG2F(rs) - posv[row]) * (0.69314718055994531f / (float)N);
        #pragma unroll
        for (int o = 32; o; o >>= 1) acc += __shfl_xor(acc, o);
        if ((tid & 63) == 0) atomicAdd(out, acc);
    }
}

// ---------------------------------------------------------------- launch
extern "C" void kernel_launch(void* const* d_in, const int* in_sizes, int n_in,
                              void* d_out, int out_size, void* d_ws, size_t ws_size,
                              hipStream_t stream)
{
    const float* z1 = (const float*)d_in[0];
    const float* z2 = (const float*)d_in[1];
    const int N = in_sizes[0] / DDIM;   // 16384

    char* ws = (char*)d_ws;
    __hip_bfloat16* z1f = (__hip_bfloat16*)ws;                  // N*128 B (2 MB)
    __hip_bfloat16* z2f = z1f + (size_t)N * DDIM;               // N*128 B (2 MB)
    float* rowsum = (float*)(ws + 2 * (size_t)N * DDIM * 2);    // N*4 B
    float* posv   = rowsum + N;                                 // N*4 B
    int*   cnt    = (int*)(posv + N);                           // 64*4 B

    const float kScale = 28.853900817779268f;   // log2(e) / 0.05

    norm_frag_kernel<<<N / 16, 256, 0, stream>>>(z1, z2, z1f, z2f, rowsum,
                                                 posv, cnt, (float*)d_out,
                                                 kScale, N);

    dim3 grid(N / BM, CS);
    infonce_main_kernel<<<grid, NW * 64, 0, stream>>>(z1f, z2f, rowsum, posv,
                                                      cnt, (float*)d_out, N);
}